// Round 4
// baseline (857.214 us; speedup 1.0000x reference)
//
#include <hip/hip_runtime.h>

typedef __bf16 bf16x8 __attribute__((ext_vector_type(8)));
typedef __bf16 bf16x4 __attribute__((ext_vector_type(4)));
typedef float  f32x4  __attribute__((ext_vector_type(4)));

// ---------- problem constants ----------
constexpr int DIL[9]   = {99,200,200,200,200,200,200,200,200};
constexpr int DOL[9]   = {200,200,200,101,200,200,200,200,1};
constexpr int KTL[9]   = {4,7,7,7,8,7,7,7,7};
constexpr int NTL[9]   = {13,13,13,7,13,13,13,13,1};
constexpr int NT0L[9]  = {7,7,7,4,7,7,7,7,1};   // N-tiles wave-group ng=0
constexpr int NT1L[9]  = {6,6,6,3,6,6,6,6,0};   // N-tiles wave-group ng=1
constexpr int NPADL[9] = {208,208,208,112,208,208,208,208,16};
constexpr long long PERML[9] = {26624,46592,46592,25088,53248,46592,46592,46592,3584}; // KT*NT*512 elems/member
constexpr long long WOFFL[9] = {0,638976,1757184,2875392,3477504,4755456,5873664,6991872,8110080};
constexpr int BOFFL[9] = {0,4992,9984,14976,17664,22656,27648,32640,37632};
constexpr int CUMTB[9] = {0,312,858,1404,1698,2322,2868,3414,3960}; // pack W-blocks cumulative (all /256 aligned)

// workspace layout (bytes)
constexpr size_t WS_ANCH = 0;
constexpr size_t WS_BIAS = 512;
constexpr size_t WS_W    = 152576;

__device__ __forceinline__ unsigned short f2bf(float f) {
  union { float f; unsigned u; } v; v.f = f;
  unsigned r = v.u + 0x7fffu + ((v.u >> 16) & 1u);   // RTNE
  return (unsigned short)(r >> 16);
}

__device__ __forceinline__ float sp100(float x) {
  float e = __expf(-100.f * fabsf(x));
  return fmaxf(x, 0.f) + 0.01f * __logf(1.f + e);
}

// ---------- combined prep: weight/bias pack + pred zero + anchors MLP ----------
struct PrepArgs {
  const float* ew[9]; const float* eb[9];
  const float* lat; const float* ac;
  const float* pw0; const float* pb0;
  const float* pw1; const float* pb1;
  const float* pw2; const float* pb2;
};

__global__ void prep_k(PrepArgs a, unsigned short* __restrict__ wsW,
                       float* __restrict__ wsBias, float* __restrict__ wsAnch,
                       float* __restrict__ out) {
  const int bid = blockIdx.x, t = threadIdx.x;
  if (bid < 4002) {
    // weight pack -> fragment-major: [m][kt][nt][lane][8]
    int L = 0;
#pragma unroll
    for (int l = 1; l < 9; ++l) if (bid >= CUMTB[l]) L = l;
    const int NT = NTL[L], DI = DIL[L], DO = DOL[L];
    const int perm = KTL[L] * NT * 64;             // threads per member
    long tid = (long)(bid - CUMTB[L]) * 256 + t;
    int m = (int)(tid / perm);
    int q = (int)(tid - (long)m * perm);
    int f = q >> 6;                                 // frag = kt*NT + nt
    int lane = q & 63;
    int kt = f / NT, nt = f - kt * NT;
    int o  = nt * 16 + (lane & 15);
    int k0 = kt * 32 + (lane >> 4) * 8;
    float sc = (L == 4) ? 0.70710678118654752f : 1.0f;
    const float* wrow = a.ew[L] + ((long)m * DO + o) * DI;
    unsigned short ov[8];
#pragma unroll
    for (int j = 0; j < 8; ++j) {
      int k = k0 + j, ks;
      if (L == 4) ks = (k < 128) ? (k < 101 ? k : -1) : (k < 227 ? k - 27 : -1);
      else        ks = (k < DI) ? k : -1;
      float v = (o < DO && ks >= 0) ? wrow[ks] * sc : 0.f;
      ov[j] = f2bf(v);
    }
    *(uint4*)(wsW + WOFFL[L] + (long)m * PERML[L] + ((long)f * 64 + lane) * 8) = *(uint4*)ov;
  } else if (bid < 4151) {
    int b = (bid - 4002) * 256 + t;
    if (b < 38016) {
      int L = 0;
#pragma unroll
      for (int l = 1; l < 9; ++l) if (b >= BOFFL[l]) L = l;
      int NP = NPADL[L], DO = DOL[L];
      int r = b - BOFFL[L];
      int m = r / NP, o = r - m * NP;
      wsBias[b] = (o < DO) ? a.eb[L][m * DO + o] : 0.f;
    }
  } else if (bid < 4167) {
    out[(bid - 4151) * 256 + t] = 0.f;             // pred zero-init
  } else {
    // anchors MLP (1 block)
    __shared__ float g[64], h1[256], h2[256];
    if (t < 64) g[t] = a.lat[t];
    __syncthreads();
    { float s = a.pb0[t]; for (int i = 0; i < 64;  ++i) s += g[i]  * a.pw0[i*256 + t]; h1[t] = fmaxf(s, 0.f); }
    __syncthreads();
    { float s = a.pb1[t]; for (int i = 0; i < 256; ++i) s += h1[i] * a.pw1[i*256 + t]; h2[t] = fmaxf(s, 0.f); }
    __syncthreads();
    if (t < 117) {
      float s = a.pb2[t];
      for (int i = 0; i < 256; ++i) s += h2[i] * a.pw2[i*117 + t];
      s += a.ac[t];
      wsAnch[t] = s; out[4096 + t] = s;
    } else if (t < 120) {
      wsAnch[t] = 0.f;
    }
  }
}

// ---------- fused ensemble MLP ----------
// LDS layout: uint2 slot (g,p) = channels [4g..4g+3] of point p, idx = g*64 + (p ^ (g&15)).
__device__ __forceinline__ int xsw(int g, int p) { return g * 64 + (p ^ (g & 15)); }

template<int L, int KTi>
__device__ __forceinline__ void readA(int l15, int hi2, int mg,
    const uint2* __restrict__ X, const uint2* __restrict__ X0, bf16x8* __restrict__ dst)
{
  constexpr bool fx0 = (L == 0) || (L == 4 && KTi >= 4);
  constexpr int ktt = (L == 4 && KTi >= 4) ? (KTi - 4) : KTi;
  const uint2* __restrict__ src = fx0 ? X0 : X;
#pragma unroll
  for (int mf = 0; mf < 2; ++mf) {
    int gg = ktt * 8 + hi2 * 2;
    int p  = mg * 32 + mf * 16 + l15;
    uint2 q0 = src[xsw(gg, p)];
    uint2 q1 = src[xsw(gg + 1, p)];
    uint4 q = make_uint4(q0.x, q0.y, q1.x, q1.y);
    dst[mf] = *(bf16x8*)&q;
  }
}

// Computes one layer's MFMAs + epilogue VALU (bias+softplus+pack) into pk/sdfv.
// LDS writes happen OUTSIDE (writeL), so in-loop LDS reads are race-free.
// Also refills b0 with next layer's kt=0 B-fragments (latency hidden by epilogue).
template<int L, int NTG, int NTB, int LN, int NTGn, int NTBn>
__device__ __forceinline__ void runLayer(int l15, int hi2, int mg, int lane, int m,
    const uint2* __restrict__ X, const uint2* __restrict__ X0,
    const unsigned short* __restrict__ Wp, const float* __restrict__ Bp,
    bf16x8* __restrict__ b0, uint2 pk[2][7], float* __restrict__ sdfv)
{
  constexpr int KT = KTL[L], NT = NTL[L];
  const unsigned short* __restrict__ Wml = Wp + WOFFL[L] + (long)m * PERML[L] + lane * 8;

  f32x4 acc[2][NTG];
#pragma unroll
  for (int mf = 0; mf < 2; ++mf)
#pragma unroll
    for (int nt = 0; nt < NTG; ++nt) acc[mf][nt] = f32x4{0.f, 0.f, 0.f, 0.f};

  bf16x8 bfr[2][NTG];
  bf16x8 afr[2][2];
#pragma unroll
  for (int nt = 0; nt < NTG; ++nt) bfr[0][nt] = b0[nt];
  readA<L, 0>(l15, hi2, mg, X, X0, afr[0]);

#define KSTEP(kt)                                                                   \
  if constexpr ((kt) < KT) {                                                        \
    if constexpr ((kt) + 1 < KT) {                                                  \
      constexpr int kn = ((kt) + 1 < KT) ? (kt) + 1 : 0;                            \
      _Pragma("unroll")                                                             \
      for (int nt = 0; nt < NTG; ++nt)                                              \
        bfr[kn & 1][nt] = *(const bf16x8*)(Wml + (long)(kn * NT + NTB + nt) * 512); \
      readA<L, kn>(l15, hi2, mg, X, X0, afr[kn & 1]);                               \
    }                                                                               \
    _Pragma("unroll")                                                               \
    for (int nt = 0; nt < NTG; ++nt) {                                              \
      acc[0][nt] = __builtin_amdgcn_mfma_f32_16x16x32_bf16(bfr[(kt)&1][nt], afr[(kt)&1][0], acc[0][nt], 0, 0, 0); \
      acc[1][nt] = __builtin_amdgcn_mfma_f32_16x16x32_bf16(bfr[(kt)&1][nt], afr[(kt)&1][1], acc[1][nt], 0, 0, 0); \
    }                                                                               \
  }
  KSTEP(0) KSTEP(1) KSTEP(2) KSTEP(3) KSTEP(4) KSTEP(5) KSTEP(6) KSTEP(7)
#undef KSTEP

  // cross-layer prefetch: next layer's kt=0 B-fragments
  if constexpr (NTGn > 0) {
    const unsigned short* __restrict__ Wmn = Wp + WOFFL[LN] + (long)m * PERML[LN] + lane * 8;
#pragma unroll
    for (int nt = 0; nt < NTGn; ++nt)
      b0[nt] = *(const bf16x8*)(Wmn + (long)(NTBn + nt) * 512);
  }

  // epilogue VALU (before barrier): bias + softplus100 + bf16 pack
  const float* Bm = Bp + BOFFL[L] + m * NPADL[L];
#pragma unroll
  for (int nt = 0; nt < NTG; ++nt) {
    int c0 = (NTB + nt) * 16 + hi2 * 4;
    float4 bb = *(const float4*)(Bm + c0);
#pragma unroll
    for (int mf = 0; mf < 2; ++mf) {
      float v0 = acc[mf][nt][0] + bb.x;
      float v1 = acc[mf][nt][1] + bb.y;
      float v2 = acc[mf][nt][2] + bb.z;
      float v3 = acc[mf][nt][3] + bb.w;
      if constexpr (L < 8) {
        v0 = sp100(v0); v1 = sp100(v1); v2 = sp100(v2); v3 = sp100(v3);
        bf16x4 w; w[0] = (__bf16)v0; w[1] = (__bf16)v1; w[2] = (__bf16)v2; w[3] = (__bf16)v3;
        pk[mf][nt] = *(uint2*)&w;
      } else {
        sdfv[mf] = v0;   // channel 0 (hi2==0, reg 0 lanes hold it)
      }
    }
  }
}

template<int L, int NTG, int NTB>
__device__ __forceinline__ void writeL(int l15, int hi2, int mg,
    uint2* __restrict__ X, const uint2 pk[2][7], const float* __restrict__ sdfv,
    float* __restrict__ sdfS)
{
  if constexpr (L < 8) {
#pragma unroll
    for (int nt = 0; nt < NTG; ++nt) {
      int c0 = (NTB + nt) * 16 + hi2 * 4;
      int g = c0 >> 2;
#pragma unroll
      for (int mf = 0; mf < 2; ++mf) {
        int p = mg * 32 + mf * 16 + l15;
        X[xsw(g, p)] = pk[mf][nt];
      }
    }
  } else {
    if (hi2 == 0) {
#pragma unroll
      for (int mf = 0; mf < 2; ++mf) sdfS[mg * 32 + mf * 16 + l15] = sdfv[mf];
    }
  }
}

__global__ __launch_bounds__(256, 3) void mlp_k(
    const float* __restrict__ xyz, const float* __restrict__ lat,
    const float* __restrict__ anch, const unsigned short* __restrict__ Wp,
    const float* __restrict__ Bp, float* __restrict__ pred)
{
  __shared__ uint2 X[56 * 64];    // 224 ch x 64 pts
  __shared__ uint2 X0[32 * 64];   // 128 ch x 64 pts (inp_net)
  __shared__ float anchS[120];
  __shared__ float sdfS[64];

  const int t = threadIdx.x;
  const int lane = t & 63, wid = t >> 6;
  const int l15 = lane & 15, hi2 = lane >> 4;
  const int mg = wid & 1, ng = wid >> 1;
  const int e  = blockIdx.x % 40;           // member<->XCD affinity (e mod 8 == XCD)
  const int pt = blockIdx.x / 40;
  const int n0 = pt * 64;
  const int m  = (e < 32) ? (e >> 1) : (e - 16);
  const float mir = (e < 32 && (e & 1)) ? -1.f : 1.f;

  bf16x8 b0[7];
  uint2  pk[2][7];
  float  sdfv[2];

  // earliest possible B0 prefetch for layer 0 (hidden behind staging + barrier)
  {
    const unsigned short* __restrict__ W0 = Wp + WOFFL[0] + (long)m * PERML[0] + lane * 8;
    if (ng == 0) {
#pragma unroll
      for (int nt = 0; nt < 7; ++nt) b0[nt] = *(const bf16x8*)(W0 + (long)nt * 512);
    } else {
#pragma unroll
      for (int nt = 0; nt < 6; ++nt) b0[nt] = *(const bf16x8*)(W0 + (long)(7 + nt) * 512);
    }
  }

  // zero pad groups (feed MFMA against zero weights; must be finite)
  for (int i = 52 * 64 + t; i < 56 * 64; i += 256) X[i]  = make_uint2(0u, 0u);
  for (int i = 24 * 64 + t; i < 32 * 64; i += 256) X0[i] = make_uint2(0u, 0u);
  if (t < 120) anchS[t] = anch[t];
  __syncthreads();

  // stage inp_net (99 ch) for 64 points into X0
  const float ax = anchS[e * 3], ay = anchS[e * 3 + 1], az = anchS[e * 3 + 2];
  for (int it = 0; it < 32; ++it) {
    int row = it * 2 + (t >> 7);
    int c = t & 127;
    long n = n0 + row;
    if (c < 99) {
      float v;
      if (c >= 67)      v = lat[n * 1344 + 64 + e * 32 + (c - 67)];
      else if (c >= 3)  v = lat[n * 1344 + (c - 3)];
      else {
        v = xyz[n * 3 + c] - ((c == 0) ? ax : (c == 1) ? ay : az);
        if (c == 0) v *= mir;
      }
      int g = c >> 2;
      ((unsigned short*)&X0[xsw(g, row)])[c & 3] = f2bf(v);
    }
  }
  __syncthreads();

#define RUNL(L, LN)                                                                          \
  do {                                                                                       \
    if (ng == 0)                                                                             \
      runLayer<L, NT0L[L], 0, LN, (LN == L ? 0 : NT0L[LN]), 0>(                              \
          l15, hi2, mg, lane, m, X, X0, Wp, Bp, b0, pk, sdfv);                               \
    else {                                                                                   \
      if constexpr (NT1L[L] > 0)                                                             \
        runLayer<L, (NT1L[L] > 0 ? NT1L[L] : 1), NT0L[L], LN,                                \
                 (LN == L ? 0 : NT1L[LN]), NT0L[LN]>(                                        \
            l15, hi2, mg, lane, m, X, X0, Wp, Bp, b0, pk, sdfv);                             \
    }                                                                                        \
    __syncthreads();                                                                         \
    if (ng == 0)                                                                             \
      writeL<L, NT0L[L], 0>(l15, hi2, mg, X, pk, sdfv, sdfS);                                \
    else {                                                                                   \
      if constexpr (NT1L[L] > 0)                                                             \
        writeL<L, (NT1L[L] > 0 ? NT1L[L] : 1), NT0L[L]>(l15, hi2, mg, X, pk, sdfv, sdfS);    \
    }                                                                                        \
    __syncthreads();                                                                         \
  } while (0)

  RUNL(0, 1); RUNL(1, 2); RUNL(2, 3); RUNL(3, 4); RUNL(4, 5);
  RUNL(5, 6); RUNL(6, 7); RUNL(7, 8); RUNL(8, 8);
#undef RUNL

  // distance softmax over 40 anchors + atomic blend
  if (t < 64) {
    long n = n0 + t;
    float px = xyz[n * 3], py = xyz[n * 3 + 1], pz = xyz[n * 3 + 2];
    float den = 1e-6f + __expf(-20.f);
    for (int j = 0; j < 39; ++j) {
      float dx = anchS[j * 3] - px, dy = anchS[j * 3 + 1] - py, dz = anchS[j * 3 + 2] - pz;
      float d = sqrtf(dx * dx + dy * dy + dz * dz) + 1e-5f;
      den += __expf(-100.f * d * d);
    }
    float num;
    if (e == 39) num = __expf(-20.f);
    else {
      float dx = anchS[e * 3] - px, dy = anchS[e * 3 + 1] - py, dz = anchS[e * 3 + 2] - pz;
      float d = sqrtf(dx * dx + dy * dy + dz * dz) + 1e-5f;
      num = __expf(-100.f * d * d);
    }
    atomicAdd(&pred[n], (num / den) * sdfS[t]);
  }
}

extern "C" void kernel_launch(void* const* d_in, const int* in_sizes, int n_in,
                              void* d_out, int out_size, void* d_ws, size_t ws_size,
                              hipStream_t stream) {
  PrepArgs a;
  const float* xyz = (const float*)d_in[0];
  a.lat = (const float*)d_in[1];
  a.ac  = (const float*)d_in[2];
  a.pw0 = (const float*)d_in[3]; a.pb0 = (const float*)d_in[4];
  a.pw1 = (const float*)d_in[5]; a.pb1 = (const float*)d_in[6];
  a.pw2 = (const float*)d_in[7]; a.pb2 = (const float*)d_in[8];
  for (int l = 0; l < 9; ++l) { a.ew[l] = (const float*)d_in[9 + 2*l]; a.eb[l] = (const float*)d_in[10 + 2*l]; }

  float* out = (float*)d_out;                 // [0,4096) pred, [4096,4213) anch
  char* ws = (char*)d_ws;
  float* wsAnch = (float*)(ws + WS_ANCH);
  float* wsBias = (float*)(ws + WS_BIAS);
  unsigned short* wsW = (unsigned short*)(ws + WS_W);

  prep_k<<<4168, 256, 0, stream>>>(a, wsW, wsBias, wsAnch, out);
  mlp_k<<<2560, 256, 0, stream>>>(xyz, a.lat, wsAnch, wsW, wsBias, out);
}

// Round 5
// 543.140 us; speedup vs baseline: 1.5783x; 1.5783x over previous
//
#include <hip/hip_runtime.h>

typedef __bf16 bf16x8 __attribute__((ext_vector_type(8)));
typedef __bf16 bf16x4 __attribute__((ext_vector_type(4)));
typedef float  f32x4  __attribute__((ext_vector_type(4)));

// ---------- problem constants ----------
constexpr int DIL[9]   = {99,200,200,200,200,200,200,200,200};
constexpr int DOL[9]   = {200,200,200,101,200,200,200,200,1};
constexpr int KTL[9]   = {4,7,7,7,8,7,7,7,7};
constexpr int NTL[9]   = {13,13,13,7,13,13,13,13,1};
constexpr int NPADL[9] = {208,208,208,112,208,208,208,208,16};
constexpr long long PERML[9] = {26624,46592,46592,25088,53248,46592,46592,46592,3584}; // KT*NT*512 elems/member
constexpr long long WOFFL[9] = {0,638976,1757184,2875392,3477504,4755456,5873664,6991872,8110080};
constexpr int BOFFL[9] = {0,4992,9984,14976,17664,22656,27648,32640,37632};
constexpr int CUMTB[9] = {0,312,858,1404,1698,2322,2868,3414,3960};
constexpr int SB0L[9]  = {0,0,1,0,1,1,0,1,0};   // WB buffer holding slice 0 at layer entry

// workspace layout (bytes)
constexpr size_t WS_ANCH = 0;
constexpr size_t WS_BIAS = 512;
constexpr size_t WS_W    = 152576;

__device__ __forceinline__ unsigned short f2bf(float f) {
  union { float f; unsigned u; } v; v.f = f;
  unsigned r = v.u + 0x7fffu + ((v.u >> 16) & 1u);   // RTNE
  return (unsigned short)(r >> 16);
}

__device__ __forceinline__ float sp100(float x) {
  float e = __expf(-100.f * fabsf(x));
  return fmaxf(x, 0.f) + 0.01f * __logf(1.f + e);
}

// async global->LDS DMA, 16B per lane; LDS dest is wave-uniform base + lane*16
__device__ __forceinline__ void gl_lds16(const void* g, void* l) {
  __builtin_amdgcn_global_load_lds(
      (const __attribute__((address_space(1))) void*)g,
      (__attribute__((address_space(3))) void*)l, 16, 0, 0);
}

// stage one kt-slice (F fragments of 1KB); fragments round-robin over waves
__device__ __forceinline__ void dmaS(const unsigned short* __restrict__ src,
                                     uint4* __restrict__ dst, int lane, int wid, int F) {
  for (int f = wid; f < F; f += 4)
    gl_lds16(src + (long)f * 512 + lane * 8, dst + f * 64);
}

// ---------- combined prep: weight/bias pack + pred zero + anchors MLP ----------
struct PrepArgs {
  const float* ew[9]; const float* eb[9];
  const float* lat; const float* ac;
  const float* pw0; const float* pb0;
  const float* pw1; const float* pb1;
  const float* pw2; const float* pb2;
};

__global__ void prep_k(PrepArgs a, unsigned short* __restrict__ wsW,
                       float* __restrict__ wsBias, float* __restrict__ wsAnch,
                       float* __restrict__ out) {
  const int bid = blockIdx.x, t = threadIdx.x;
  if (bid < 4002) {
    // weight pack -> fragment-major: [m][kt][nt][lane][8]
    int L = 0;
#pragma unroll
    for (int l = 1; l < 9; ++l) if (bid >= CUMTB[l]) L = l;
    const int NT = NTL[L], DI = DIL[L], DO = DOL[L];
    const int perm = KTL[L] * NT * 64;
    long tid = (long)(bid - CUMTB[L]) * 256 + t;
    int m = (int)(tid / perm);
    int q = (int)(tid - (long)m * perm);
    int f = q >> 6;
    int lane = q & 63;
    int kt = f / NT, nt = f - kt * NT;
    int o  = nt * 16 + (lane & 15);
    int k0 = kt * 32 + (lane >> 4) * 8;
    float sc = (L == 4) ? 0.70710678118654752f : 1.0f;
    const float* wrow = a.ew[L] + ((long)m * DO + o) * DI;
    unsigned short ov[8];
#pragma unroll
    for (int j = 0; j < 8; ++j) {
      int k = k0 + j, ks;
      if (L == 4) ks = (k < 128) ? (k < 101 ? k : -1) : (k < 227 ? k - 27 : -1);
      else        ks = (k < DI) ? k : -1;
      float v = (o < DO && ks >= 0) ? wrow[ks] * sc : 0.f;
      ov[j] = f2bf(v);
    }
    *(uint4*)(wsW + WOFFL[L] + (long)m * PERML[L] + ((long)f * 64 + lane) * 8) = *(uint4*)ov;
  } else if (bid < 4151) {
    int b = (bid - 4002) * 256 + t;
    if (b < 38016) {
      int L = 0;
#pragma unroll
      for (int l = 1; l < 9; ++l) if (b >= BOFFL[l]) L = l;
      int NP = NPADL[L], DO = DOL[L];
      int r = b - BOFFL[L];
      int m = r / NP, o = r - m * NP;
      wsBias[b] = (o < DO) ? a.eb[L][m * DO + o] : 0.f;
    }
  } else if (bid < 4167) {
    out[(bid - 4151) * 256 + t] = 0.f;             // pred zero-init
  } else {
    __shared__ float g[64], h1[256], h2[256];
    if (t < 64) g[t] = a.lat[t];
    __syncthreads();
    { float s = a.pb0[t]; for (int i = 0; i < 64;  ++i) s += g[i]  * a.pw0[i*256 + t]; h1[t] = fmaxf(s, 0.f); }
    __syncthreads();
    { float s = a.pb1[t]; for (int i = 0; i < 256; ++i) s += h1[i] * a.pw1[i*256 + t]; h2[t] = fmaxf(s, 0.f); }
    __syncthreads();
    if (t < 117) {
      float s = a.pb2[t];
      for (int i = 0; i < 256; ++i) s += h2[i] * a.pw2[i*117 + t];
      s += a.ac[t];
      wsAnch[t] = s; out[4096 + t] = s;
    } else if (t < 120) {
      wsAnch[t] = 0.f;
    }
  }
}

// ---------- fused ensemble MLP ----------
// Activation LDS: uint2 slot (g,p) = channels [4g..4g+3] of point p, idx = g*64 + (p ^ (g&15)).
__device__ __forceinline__ int xsw(int g, int p) { return g * 64 + (p ^ (g & 15)); }

// One layer: kt-loop {DMA next slice | ds_read A,B | MFMA | barrier}, then epilogue.
// P=0: NTG=4 wave (wid 0); P=1: NTG=3 waves (wid 1..3). ntb runtime.
template<int L, int P, int LN>
__device__ __forceinline__ void runLayer(int lane, int l15, int hi2, int wid, int m, int ntb,
    uint2* __restrict__ X, const uint2* __restrict__ X0, uint4* __restrict__ WBf,
    const unsigned short* __restrict__ Wp, const float* __restrict__ Bp,
    float* __restrict__ sdfS)
{
  constexpr int KT = KTL[L], NT = NTL[L];
  constexpr int NTG = (NT == 13) ? (P == 0 ? 4 : 3) : (NT == 7 ? 2 : 1);
  const unsigned short* __restrict__ Wm = Wp + WOFFL[L] + (long)m * PERML[L];

  f32x4 acc[4][NTG];
#pragma unroll
  for (int mf = 0; mf < 4; ++mf)
#pragma unroll
    for (int nt = 0; nt < NTG; ++nt) acc[mf][nt] = f32x4{0.f, 0.f, 0.f, 0.f};

  int sb = SB0L[L];
  for (int kt = 0; kt < KT; ++kt) {
    // async prefetch of next slice (or next layer's slice 0) into WB[sb^1]
    if (kt + 1 < KT) {
      dmaS(Wm + (long)(kt + 1) * (NT * 512), WBf + (sb ^ 1) * (13 * 64), lane, wid, NT);
    } else if constexpr (LN >= 0) {
      dmaS(Wp + WOFFL[LN] + (long)m * PERML[LN], WBf + (sb ^ 1) * (13 * 64), lane, wid, NTL[LN]);
    }
    // A fragments (activations; cols=points)
    const uint2* __restrict__ srcA = (L == 0 || (L == 4 && kt >= 4)) ? X0 : X;
    int ktt = (L == 4 && kt >= 4) ? kt - 4 : kt;
    int gg = ktt * 8 + hi2 * 2;
    bf16x8 afr[4];
#pragma unroll
    for (int mf = 0; mf < 4; ++mf) {
      int p = mf * 16 + l15;
      uint2 q0 = srcA[xsw(gg, p)];
      uint2 q1 = srcA[xsw(gg + 1, p)];
      uint4 q = make_uint4(q0.x, q0.y, q1.x, q1.y);
      afr[mf] = *(bf16x8*)&q;
    }
    // B fragments from staged slice (contiguous 16B/lane -> conflict-free b128)
    const uint4* __restrict__ wb = WBf + sb * (13 * 64) + lane;
    bf16x8 bfr[NTG];
#pragma unroll
    for (int nt = 0; nt < NTG; ++nt) {
      uint4 q = wb[(ntb + nt) * 64];
      bfr[nt] = *(bf16x8*)&q;
    }
#pragma unroll
    for (int nt = 0; nt < NTG; ++nt)
#pragma unroll
      for (int mf = 0; mf < 4; ++mf)
        acc[mf][nt] = __builtin_amdgcn_mfma_f32_16x16x32_bf16(bfr[nt], afr[mf], acc[mf][nt], 0, 0, 0);
    __syncthreads();   // drains DMA (vmcnt0) -> slice sb^1 complete; X reads done
    sb ^= 1;
  }

  // epilogue: bias + softplus + pack + LDS write (X reads all done at last barrier)
  const float* __restrict__ Bm = Bp + BOFFL[L] + m * NPADL[L];
  if constexpr (L < 8) {
    uint2 pk[4][NTG];
#pragma unroll
    for (int nt = 0; nt < NTG; ++nt) {
      int c0 = (ntb + nt) * 16 + hi2 * 4;
      float4 bb = *(const float4*)(Bm + c0);
#pragma unroll
      for (int mf = 0; mf < 4; ++mf) {
        float v0 = sp100(acc[mf][nt][0] + bb.x);
        float v1 = sp100(acc[mf][nt][1] + bb.y);
        float v2 = sp100(acc[mf][nt][2] + bb.z);
        float v3 = sp100(acc[mf][nt][3] + bb.w);
        bf16x4 w; w[0] = (__bf16)v0; w[1] = (__bf16)v1; w[2] = (__bf16)v2; w[3] = (__bf16)v3;
        pk[mf][nt] = *(uint2*)&w;
      }
    }
#pragma unroll
    for (int nt = 0; nt < NTG; ++nt) {
      int g = ((ntb + nt) * 16 + hi2 * 4) >> 2;
#pragma unroll
      for (int mf = 0; mf < 4; ++mf)
        X[xsw(g, mf * 16 + l15)] = pk[mf][nt];
    }
  } else {
    float b0 = Bm[0];
    if (hi2 == 0) {
#pragma unroll
      for (int mf = 0; mf < 4; ++mf) sdfS[mf * 16 + l15] = acc[mf][0][0] + b0;
    }
  }
  __syncthreads();
}

template<int P>
__device__ __forceinline__ void runAll(int lane, int l15, int hi2, int wid, int m,
    uint2* __restrict__ X, const uint2* __restrict__ X0, uint4* __restrict__ WBf,
    const unsigned short* __restrict__ Wp, const float* __restrict__ Bp,
    float* __restrict__ sdfS)
{
  const int ntb13 = wid * 3 + (wid > 0 ? 1 : 0);   // {0,4,7,10}
  const int ntb7  = (wid < 3) ? 2 * wid : 5;       // {0,2,4,5} (wave3 dup of frag5: benign)
  runLayer<0, P, 1>(lane, l15, hi2, wid, m, ntb13, X, X0, WBf, Wp, Bp, sdfS);
  runLayer<1, P, 2>(lane, l15, hi2, wid, m, ntb13, X, X0, WBf, Wp, Bp, sdfS);
  runLayer<2, P, 3>(lane, l15, hi2, wid, m, ntb13, X, X0, WBf, Wp, Bp, sdfS);
  runLayer<3, P, 4>(lane, l15, hi2, wid, m, ntb7,  X, X0, WBf, Wp, Bp, sdfS);
  runLayer<4, P, 5>(lane, l15, hi2, wid, m, ntb13, X, X0, WBf, Wp, Bp, sdfS);
  runLayer<5, P, 6>(lane, l15, hi2, wid, m, ntb13, X, X0, WBf, Wp, Bp, sdfS);
  runLayer<6, P, 7>(lane, l15, hi2, wid, m, ntb13, X, X0, WBf, Wp, Bp, sdfS);
  runLayer<7, P, 8>(lane, l15, hi2, wid, m, ntb13, X, X0, WBf, Wp, Bp, sdfS);
  runLayer<8, P, -1>(lane, l15, hi2, wid, m, 0,    X, X0, WBf, Wp, Bp, sdfS);
}

__global__ __launch_bounds__(256, 2) void mlp_k(
    const float* __restrict__ xyz, const float* __restrict__ lat,
    const float* __restrict__ anch, const unsigned short* __restrict__ Wp,
    const float* __restrict__ Bp, float* __restrict__ pred)
{
  __shared__ uint2 X[56 * 64];        // 224 ch x 64 pts (28.7 KB)
  __shared__ uint2 X0[32 * 64];       // 128 ch x 64 pts inp_net (16.4 KB)
  __shared__ uint4 WB[2][13 * 64];    // weight slices, 2 x 13 KB
  __shared__ float anchS[120];
  __shared__ float sdfS[64];

  const int t = threadIdx.x;
  const int lane = t & 63, wid = t >> 6;
  const int l15 = lane & 15, hi2 = lane >> 4;
  const int e  = blockIdx.x % 40;          // member<->XCD affinity (40 % 8 == 0)
  const int pt = blockIdx.x / 40;
  const int n0 = pt * 64;
  const int m  = (e < 32) ? (e >> 1) : (e - 16);
  const float mir = (e < 32 && (e & 1)) ? -1.f : 1.f;

  // issue layer-0 slice-0 DMA immediately (drained at first barrier)
  dmaS(Wp + WOFFL[0] + (long)m * PERML[0], &WB[0][0], lane, wid, 13);

  // zero pad groups (feed MFMA against zero weights; must be finite)
  for (int i = 52 * 64 + t; i < 56 * 64; i += 256) X[i]  = make_uint2(0u, 0u);
  for (int i = 24 * 64 + t; i < 32 * 64; i += 256) X0[i] = make_uint2(0u, 0u);
  if (t < 120) anchS[t] = anch[t];
  __syncthreads();

  // stage inp_net (99 ch) for 64 points into X0
  const float ax = anchS[e * 3], ay = anchS[e * 3 + 1], az = anchS[e * 3 + 2];
  for (int it = 0; it < 32; ++it) {
    int row = it * 2 + (t >> 7);
    int c = t & 127;
    long n = n0 + row;
    if (c < 99) {
      float v;
      if (c >= 67)      v = lat[n * 1344 + 64 + e * 32 + (c - 67)];
      else if (c >= 3)  v = lat[n * 1344 + (c - 3)];
      else {
        v = xyz[n * 3 + c] - ((c == 0) ? ax : (c == 1) ? ay : az);
        if (c == 0) v *= mir;
      }
      int g = c >> 2;
      ((unsigned short*)&X0[xsw(g, row)])[c & 3] = f2bf(v);
    }
  }
  __syncthreads();

  if (wid == 0) runAll<0>(lane, l15, hi2, wid, m, X, X0, &WB[0][0], Wp, Bp, sdfS);
  else          runAll<1>(lane, l15, hi2, wid, m, X, X0, &WB[0][0], Wp, Bp, sdfS);

  // distance softmax over 40 anchors + atomic blend
  if (t < 64) {
    long n = n0 + t;
    float px = xyz[n * 3], py = xyz[n * 3 + 1], pz = xyz[n * 3 + 2];
    float den = 1e-6f + __expf(-20.f);
    for (int j = 0; j < 39; ++j) {
      float dx = anchS[j * 3] - px, dy = anchS[j * 3 + 1] - py, dz = anchS[j * 3 + 2] - pz;
      float d = sqrtf(dx * dx + dy * dy + dz * dz) + 1e-5f;
      den += __expf(-100.f * d * d);
    }
    float num;
    if (e == 39) num = __expf(-20.f);
    else {
      float dx = anchS[e * 3] - px, dy = anchS[e * 3 + 1] - py, dz = anchS[e * 3 + 2] - pz;
      float d = sqrtf(dx * dx + dy * dy + dz * dz) + 1e-5f;
      num = __expf(-100.f * d * d);
    }
    atomicAdd(&pred[n], (num / den) * sdfS[t]);
  }
}

extern "C" void kernel_launch(void* const* d_in, const int* in_sizes, int n_in,
                              void* d_out, int out_size, void* d_ws, size_t ws_size,
                              hipStream_t stream) {
  PrepArgs a;
  const float* xyz = (const float*)d_in[0];
  a.lat = (const float*)d_in[1];
  a.ac  = (const float*)d_in[2];
  a.pw0 = (const float*)d_in[3]; a.pb0 = (const float*)d_in[4];
  a.pw1 = (const float*)d_in[5]; a.pb1 = (const float*)d_in[6];
  a.pw2 = (const float*)d_in[7]; a.pb2 = (const float*)d_in[8];
  for (int l = 0; l < 9; ++l) { a.ew[l] = (const float*)d_in[9 + 2*l]; a.eb[l] = (const float*)d_in[10 + 2*l]; }

  float* out = (float*)d_out;                 // [0,4096) pred, [4096,4213) anch
  char* ws = (char*)d_ws;
  float* wsAnch = (float*)(ws + WS_ANCH);
  float* wsBias = (float*)(ws + WS_BIAS);
  unsigned short* wsW = (unsigned short*)(ws + WS_W);

  prep_k<<<4168, 256, 0, stream>>>(a, wsW, wsBias, wsAnch, out);
  mlp_k<<<2560, 256, 0, stream>>>(xyz, a.lat, wsAnch, wsW, wsBias, out);
}